// Round 5
// baseline (328.237 us; speedup 1.0000x reference)
//
#include <hip/hip_runtime.h>
#include <cstddef>

#define NN 50000
#define NPAD 50048            // 782 blocks * 64 rows
#define NE 800000
#define HC 128
#define OC 64
#define NL 3
#define BN_EPS 1e-5f
#define NB ((NN + 1023) / 1024)

typedef _Float16 half8 __attribute__((ext_vector_type(8)));
typedef _Float16 half4 __attribute__((ext_vector_type(4)));
typedef _Float16 h2 __attribute__((ext_vector_type(2)));
typedef float f32x4 __attribute__((ext_vector_type(4)));

// ---------------- degree / dinv ----------------
__global__ void init_cnt(int* __restrict__ cnt) {
    int i = blockIdx.x * blockDim.x + threadIdx.x;
    if (i < NN) cnt[i] = 0;
}

// count + per-edge rank (order within its dst bucket)
__global__ void count_deg(const int* __restrict__ dst, int* __restrict__ cnt,
                          int* __restrict__ rank) {
    int e = blockIdx.x * blockDim.x + threadIdx.x;
    if (e < NE) rank[e] = atomicAdd(&cnt[dst[e]], 1);
}

__global__ void calc_dinv(const int* __restrict__ cnt, float* __restrict__ dinv) {
    int i = blockIdx.x * blockDim.x + threadIdx.x;
    if (i < NN) dinv[i] = rsqrtf((float)(cnt[i] + 1));   // +1 self-loop
}

// ---------------- exclusive scan ----------------
__global__ __launch_bounds__(256) void scan1(const int* __restrict__ cnt,
                                             int* __restrict__ offs,
                                             int* __restrict__ partials) {
    __shared__ int sm[256];
    const int t = threadIdx.x;
    const int base = blockIdx.x * 1024 + t * 4;
    int c[4];
#pragma unroll
    for (int k = 0; k < 4; ++k) c[k] = (base + k < NN) ? cnt[base + k] : 0;
    int s = c[0] + c[1] + c[2] + c[3];
    sm[t] = s;
    __syncthreads();
    for (int off = 1; off < 256; off <<= 1) {
        int v = (t >= off) ? sm[t - off] : 0;
        __syncthreads();
        sm[t] += v;
        __syncthreads();
    }
    int run = sm[t] - s;
    if (t == 255) partials[blockIdx.x] = sm[255];
#pragma unroll
    for (int k = 0; k < 4; ++k) {
        if (base + k < NN) { offs[base + k] = run; run += c[k]; }
    }
}

__global__ void scan2(int* __restrict__ partials) {
    if (threadIdx.x == 0) {
        int run = 0;
        for (int i = 0; i < NB; ++i) { int v = partials[i]; partials[i] = run; run += v; }
    }
}

__global__ void scan3(int* __restrict__ offs, const int* __restrict__ partials) {
    int i = blockIdx.x * blockDim.x + threadIdx.x;
    if (i < NN) offs[i] += partials[i >> 10];
}

// ---------------- CSR fill: no atomics, single 4B scatter ----------------
__global__ void fill_csr(const int* __restrict__ src, const int* __restrict__ dst,
                         const int* __restrict__ offs, const int* __restrict__ rank,
                         int* __restrict__ csr_src) {
    int e = blockIdx.x * blockDim.x + threadIdx.x;
    if (e >= NE) return;
    csr_src[offs[dst[e]] + rank[e]] = src[e];
}

// ---------------- param prep: pack weights to MFMA B-frag order (fp16), BN fold ----------------
__global__ void pack_params(const float* __restrict__ Wg, const float* __restrict__ Wl,
                            const float* __restrict__ Wp,
                            const float* __restrict__ bg, const float* __restrict__ bl,
                            const float* __restrict__ bn_g, const float* __restrict__ bn_b,
                            const float* __restrict__ bn_rm, const float* __restrict__ bn_rv,
                            _Float16* __restrict__ wgl16,   // [3][2][2048][8]
                            _Float16* __restrict__ wpp16,   // [1024][8]
                            float* __restrict__ bsum,       // [3][128] bg+bl
                            float* __restrict__ bnsc, float* __restrict__ bnsh) // [3][128]
{
    const int tid = blockIdx.x * blockDim.x + threadIdx.x;
    if (tid < 12288) {
        const int layer = tid >> 12;
        const int gl = (tid >> 11) & 1;
        const int rem = tid & 2047;
        const int lane = rem & 63;
        const int ks = (rem >> 6) & 3;
        const int n4 = rem >> 8;
        const float* W = (gl ? Wl : Wg) + (size_t)layer * HC * HC;
        const int kbase = ks * 32 + (lane >> 4) * 8;
        const int n = n4 * 16 + (lane & 15);
        _Float16* dst = wgl16 + (size_t)tid * 8;
#pragma unroll
        for (int j = 0; j < 8; ++j) dst[j] = (_Float16)W[(size_t)(kbase + j) * HC + n];
    } else if (tid < 13312) {
        const int f = tid - 12288;
        const int lane = f & 63;
        const int ks = (f >> 6) & 3;
        const int n4 = f >> 8;
        const int kbase = ks * 32 + (lane >> 4) * 8;
        const int n = n4 * 16 + (lane & 15);
        _Float16* dst = wpp16 + (size_t)f * 8;
#pragma unroll
        for (int j = 0; j < 8; ++j) dst[j] = (_Float16)Wp[(size_t)(kbase + j) * OC + n];
    } else if (tid < 13312 + NL * HC) {
        const int i = tid - 13312;
        bsum[i] = bg[i] + bl[i];
        const float sc = bn_g[i] * rsqrtf(bn_rv[i] + BN_EPS);
        bnsc[i] = sc;
        bnsh[i] = bn_b[i] - bn_rm[i] * sc;
    }
}

// ---------------- x fp32 -> fp16 ----------------
__global__ void conv_x16(const float* __restrict__ x, _Float16* __restrict__ x16) {
    const int i = blockIdx.x * blockDim.x + threadIdx.x;
    if (i >= NN * HC / 4) return;
    const float4 v = reinterpret_cast<const float4*>(x)[i];
    half4 o = {(_Float16)v.x, (_Float16)v.y, (_Float16)v.z, (_Float16)v.w};
    reinterpret_cast<half4*>(x16)[i] = o;
}

// ---------------- dual GEMM via MFMA ----------------
// hs16 = dinv[row] * (x@Wg)   (pre-scaled by source-side dinv)
// pre16 = x@Wl + bsum + dinv^2 * (x@Wg)   (self-loop folded, pre-BN)
__global__ __launch_bounds__(256) void gemm_dual_mfma(
    const _Float16* __restrict__ x16,
    const _Float16* __restrict__ Wgp, const _Float16* __restrict__ Wlp,
    const float* __restrict__ bsum, const float* __restrict__ dinv,
    _Float16* __restrict__ hs16, _Float16* __restrict__ pre16)
{
    const int wave = threadIdx.x >> 6;
    const int lane = threadIdx.x & 63;
    const int rowBase = blockIdx.x * 64 + wave * 16;
    const int ar = rowBase + (lane & 15);
    const int ak = (lane >> 4) * 8;

    half8 a[4];
#pragma unroll
    for (int ks = 0; ks < 4; ++ks)
        a[ks] = *reinterpret_cast<const half8*>(x16 + (size_t)ar * HC + ks * 32 + ak);

    f32x4 accG[8], accL[8];
#pragma unroll
    for (int n4 = 0; n4 < 8; ++n4) { accG[n4] = (f32x4)0.f; accL[n4] = (f32x4)0.f; }

    const half8* wg = reinterpret_cast<const half8*>(Wgp) + lane;
    const half8* wl = reinterpret_cast<const half8*>(Wlp) + lane;
#pragma unroll
    for (int n4 = 0; n4 < 8; ++n4) {
#pragma unroll
        for (int ks = 0; ks < 4; ++ks) {
            const half8 bG = wg[(n4 * 4 + ks) * 64];
            accG[n4] = __builtin_amdgcn_mfma_f32_16x16x32_f16(a[ks], bG, accG[n4], 0, 0, 0);
            const half8 bL = wl[(n4 * 4 + ks) * 64];
            accL[n4] = __builtin_amdgcn_mfma_f32_16x16x32_f16(a[ks], bL, accL[n4], 0, 0, 0);
        }
    }

    const int col = lane & 15;
    const int roff = (lane >> 4) * 4;
#pragma unroll
    for (int r = 0; r < 4; ++r) {
        const int row = rowBase + roff + r;
        if (row >= NN) continue;
        const float dv = dinv[row];
        const float selfn = dv * dv;
        _Float16* hp = hs16 + (size_t)row * HC + col;
        _Float16* xp = pre16 + (size_t)row * HC + col;
#pragma unroll
        for (int n4 = 0; n4 < 8; ++n4) {
            const float hval = accG[n4][r];
            hp[n4 * 16] = (_Float16)(dv * hval);
            xp[n4 * 16] = (_Float16)(accL[n4][r] + bsum[n4 * 16 + col] + selfn * hval);
        }
    }
}

// ---------------- CSR gather + BN + ReLU: one wave per node ----------------
// Lane l holds channels 2l, 2l+1. Edge srcs preloaded 64-wide, distributed via shfl
// so all h-row loads have early-known addresses (deep MLP).
__global__ __launch_bounds__(256) void gather_conv_bn(
    const int* __restrict__ csr_src, const int* __restrict__ offs,
    const int* __restrict__ cnt, const float* __restrict__ dinv,
    const _Float16* __restrict__ hs16, const _Float16* __restrict__ pre16,
    _Float16* __restrict__ xout16,
    const float* __restrict__ bnsc, const float* __restrict__ bnsh)
{
    const int node = (int)((blockIdx.x * blockDim.x + threadIdx.x) >> 6);
    const int lane = threadIdx.x & 63;
    if (node >= NN) return;
    const int beg = offs[node];
    const int n = cnt[node];

    float a0 = 0.f, a1 = 0.f;
    for (int j0 = 0; j0 < n; j0 += 64) {
        const int m = min(64, n - j0);
        const int sv = (lane < m) ? csr_src[beg + j0 + lane] : 0;
#pragma unroll 4
        for (int j = 0; j < m; ++j) {
            const int s = __shfl(sv, j, 64);
            const h2 hv = reinterpret_cast<const h2*>(hs16 + (size_t)s * HC)[lane];
            a0 += (float)hv[0];
            a1 += (float)hv[1];
        }
    }

    const float dv = dinv[node];
    const h2 pv = reinterpret_cast<const h2*>(pre16 + (size_t)node * HC)[lane];
    const float2 sc = reinterpret_cast<const float2*>(bnsc)[lane];
    const float2 sh = reinterpret_cast<const float2*>(bnsh)[lane];
    const float x0 = (float)pv[0] + dv * a0;
    const float x1 = (float)pv[1] + dv * a1;
    h2 o;
    o[0] = (_Float16)fmaxf(x0 * sc.x + sh.x, 0.f);
    o[1] = (_Float16)fmaxf(x1 * sc.y + sh.y, 0.f);
    reinterpret_cast<h2*>(xout16 + (size_t)node * HC)[lane] = o;
}

// ---------------- output projection via MFMA ----------------
__global__ __launch_bounds__(256) void gemm_out_mfma(
    const _Float16* __restrict__ x16, const _Float16* __restrict__ Wpp,
    const float* __restrict__ bp, float* __restrict__ out)
{
    const int wave = threadIdx.x >> 6;
    const int lane = threadIdx.x & 63;
    const int rowBase = blockIdx.x * 64 + wave * 16;
    const int ar = rowBase + (lane & 15);
    const int ak = (lane >> 4) * 8;

    half8 a[4];
#pragma unroll
    for (int ks = 0; ks < 4; ++ks)
        a[ks] = *reinterpret_cast<const half8*>(x16 + (size_t)ar * HC + ks * 32 + ak);

    f32x4 acc[4];
#pragma unroll
    for (int n4 = 0; n4 < 4; ++n4) acc[n4] = (f32x4)0.f;

    const half8* wp = reinterpret_cast<const half8*>(Wpp) + lane;
#pragma unroll
    for (int n4 = 0; n4 < 4; ++n4)
#pragma unroll
        for (int ks = 0; ks < 4; ++ks)
            acc[n4] = __builtin_amdgcn_mfma_f32_16x16x32_f16(a[ks], wp[(n4 * 4 + ks) * 64], acc[n4], 0, 0, 0);

    const int col = lane & 15;
    const int roff = (lane >> 4) * 4;
#pragma unroll
    for (int r = 0; r < 4; ++r) {
        const int row = rowBase + roff + r;
        if (row >= NN) continue;
        float* op = out + (size_t)row * OC + col;
#pragma unroll
        for (int n4 = 0; n4 < 4; ++n4)
            op[n4 * 16] = acc[n4][r] + bp[n4 * 16 + col];
    }
}

extern "C" void kernel_launch(void* const* d_in, const int* in_sizes, int n_in,
                              void* d_out, int out_size, void* d_ws, size_t ws_size,
                              hipStream_t stream) {
    const float* x    = (const float*)d_in[0];
    const int*   ei   = (const int*)d_in[1];
    const float* Wg   = (const float*)d_in[2];
    const float* bg   = (const float*)d_in[3];
    const float* Wl   = (const float*)d_in[4];
    const float* bl   = (const float*)d_in[5];
    const float* bn_g = (const float*)d_in[6];
    const float* bn_b = (const float*)d_in[7];
    const float* bn_rm= (const float*)d_in[8];
    const float* bn_rv= (const float*)d_in[9];
    const float* Wp   = (const float*)d_in[10];
    const float* bp   = (const float*)d_in[11];
    float* out = (float*)d_out;

    const int* e_src = ei;
    const int* e_dst = ei + NE;

    // workspace layout
    char* p = (char*)d_ws;
    _Float16* x16a = (_Float16*)p;            p += (size_t)NPAD * HC * 2;
    _Float16* x16b = (_Float16*)p;            p += (size_t)NPAD * HC * 2;
    _Float16* hs16 = (_Float16*)p;            p += (size_t)NPAD * HC * 2;
    _Float16* pre16= (_Float16*)p;            p += (size_t)NPAD * HC * 2;
    float* dinv    = (float*)p;               p += (size_t)NN * 4;
    int* csr_src   = (int*)p;                 p += (size_t)NE * 4;
    int* rank      = (int*)p;                 p += (size_t)NE * 4;
    int* cnt       = (int*)p;                 p += (size_t)NN * 4;
    int* offs      = (int*)p;                 p += (size_t)NN * 4;
    int* partials  = (int*)p;                 p += (size_t)NB * 4 + 64;
    _Float16* wgl16 = (_Float16*)p;           p += (size_t)12288 * 8 * 2;
    _Float16* wpp16 = (_Float16*)p;           p += (size_t)1024 * 8 * 2;
    float* bsum    = (float*)p;               p += (size_t)NL * HC * 4;
    float* bnsc    = (float*)p;               p += (size_t)NL * HC * 4;
    float* bnsh    = (float*)p;               p += (size_t)NL * HC * 4;

    const int nblk = (NN + 255) / 256;
    const int eblk = (NE + 255) / 256;

    init_cnt<<<nblk, 256, 0, stream>>>(cnt);
    count_deg<<<eblk, 256, 0, stream>>>(e_dst, cnt, rank);
    calc_dinv<<<nblk, 256, 0, stream>>>(cnt, dinv);
    scan1<<<NB, 256, 0, stream>>>(cnt, offs, partials);
    scan2<<<1, 64, 0, stream>>>(partials);
    scan3<<<nblk, 256, 0, stream>>>(offs, partials);
    fill_csr<<<eblk, 256, 0, stream>>>(e_src, e_dst, offs, rank, csr_src);

    pack_params<<<(13312 + NL * HC + 255) / 256, 256, 0, stream>>>(
        Wg, Wl, Wp, bg, bl, bn_g, bn_b, bn_rm, bn_rv,
        wgl16, wpp16, bsum, bnsc, bnsh);
    conv_x16<<<(NN * HC / 4 + 255) / 256, 256, 0, stream>>>(x, x16a);

    const int gemm_blocks = NPAD / 64;       // 782
    const int gat_blocks = (NN * 64 + 255) / 256;   // 1 wave per node

    _Float16* xin16 = x16a;
    _Float16* pp16[NL] = {x16b, x16a, x16b};
    for (int l = 0; l < NL; ++l) {
        _Float16* xnext16 = pp16[l];
        gemm_dual_mfma<<<gemm_blocks, 256, 0, stream>>>(
            xin16,
            wgl16 + (size_t)(l * 2 + 0) * 2048 * 8,
            wgl16 + (size_t)(l * 2 + 1) * 2048 * 8,
            bsum + (size_t)l * HC, dinv, hs16, pre16);
        gather_conv_bn<<<gat_blocks, 256, 0, stream>>>(
            csr_src, offs, cnt, dinv, hs16, pre16, xnext16,
            bnsc + (size_t)l * HC, bnsh + (size_t)l * HC);
        xin16 = xnext16;
    }

    gemm_out_mfma<<<gemm_blocks, 256, 0, stream>>>(xin16, wpp16, bp, out);
}

// Round 6
// 322.379 us; speedup vs baseline: 1.0182x; 1.0182x over previous
//
#include <hip/hip_runtime.h>
#include <cstddef>

#define NN 50000
#define NPAD 50048            // 782 blocks * 64 rows
#define NE 800000
#define HC 128
#define OC 64
#define NL 3
#define BN_EPS 1e-5f
#define NB ((NN + 1023) / 1024)

typedef _Float16 half8 __attribute__((ext_vector_type(8)));
typedef _Float16 half4 __attribute__((ext_vector_type(4)));
typedef _Float16 h2 __attribute__((ext_vector_type(2)));
typedef float f32x4 __attribute__((ext_vector_type(4)));

// ---------------- degree / dinv ----------------
__global__ void init_cnt(int* __restrict__ cnt) {
    int i = blockIdx.x * blockDim.x + threadIdx.x;
    if (i < NN) cnt[i] = 0;
}

// count + per-edge rank (order within its dst bucket), rank fits u16 (max deg ~50)
__global__ void count_deg(const int* __restrict__ dst, int* __restrict__ cnt,
                          unsigned short* __restrict__ rank) {
    int e = blockIdx.x * blockDim.x + threadIdx.x;
    if (e < NE) rank[e] = (unsigned short)atomicAdd(&cnt[dst[e]], 1);
}

__global__ void calc_dinv(const int* __restrict__ cnt, float* __restrict__ dinv) {
    int i = blockIdx.x * blockDim.x + threadIdx.x;
    if (i < NN) dinv[i] = rsqrtf((float)(cnt[i] + 1));   // +1 self-loop
}

// ---------------- exclusive scan ----------------
__global__ __launch_bounds__(256) void scan1(const int* __restrict__ cnt,
                                             int* __restrict__ offs,
                                             int* __restrict__ partials) {
    __shared__ int sm[256];
    const int t = threadIdx.x;
    const int base = blockIdx.x * 1024 + t * 4;
    int c[4];
#pragma unroll
    for (int k = 0; k < 4; ++k) c[k] = (base + k < NN) ? cnt[base + k] : 0;
    int s = c[0] + c[1] + c[2] + c[3];
    sm[t] = s;
    __syncthreads();
    for (int off = 1; off < 256; off <<= 1) {
        int v = (t >= off) ? sm[t - off] : 0;
        __syncthreads();
        sm[t] += v;
        __syncthreads();
    }
    int run = sm[t] - s;
    if (t == 255) partials[blockIdx.x] = sm[255];
#pragma unroll
    for (int k = 0; k < 4; ++k) {
        if (base + k < NN) { offs[base + k] = run; run += c[k]; }
    }
}

__global__ void scan2(int* __restrict__ partials) {
    if (threadIdx.x == 0) {
        int run = 0;
        for (int i = 0; i < NB; ++i) { int v = partials[i]; partials[i] = run; run += v; }
    }
}

__global__ void scan3(int* __restrict__ offs, const int* __restrict__ partials) {
    int i = blockIdx.x * blockDim.x + threadIdx.x;
    if (i < NN) offs[i] += partials[i >> 10];
}

// ---------------- CSR fill: no atomics, single 2B scatter ----------------
__global__ void fill_csr(const int* __restrict__ src, const int* __restrict__ dst,
                         const int* __restrict__ offs, const unsigned short* __restrict__ rank,
                         unsigned short* __restrict__ csr_src) {
    int e = blockIdx.x * blockDim.x + threadIdx.x;
    if (e >= NE) return;
    csr_src[offs[dst[e]] + (int)rank[e]] = (unsigned short)src[e];
}

// ---------------- param prep ----------------
__global__ void pack_params(const float* __restrict__ Wg, const float* __restrict__ Wl,
                            const float* __restrict__ Wp,
                            const float* __restrict__ bg, const float* __restrict__ bl,
                            const float* __restrict__ bn_g, const float* __restrict__ bn_b,
                            const float* __restrict__ bn_rm, const float* __restrict__ bn_rv,
                            _Float16* __restrict__ wgl16,   // [3][2][2048][8]
                            _Float16* __restrict__ wpp16,   // [1024][8]
                            float* __restrict__ bsum,       // [3][128] bg+bl
                            float* __restrict__ bnsc, float* __restrict__ bnsh) // [3][128]
{
    const int tid = blockIdx.x * blockDim.x + threadIdx.x;
    if (tid < 12288) {
        const int layer = tid >> 12;
        const int gl = (tid >> 11) & 1;
        const int rem = tid & 2047;
        const int lane = rem & 63;
        const int ks = (rem >> 6) & 3;
        const int n4 = rem >> 8;
        const float* W = (gl ? Wl : Wg) + (size_t)layer * HC * HC;
        const int kbase = ks * 32 + (lane >> 4) * 8;
        const int n = n4 * 16 + (lane & 15);
        _Float16* dst = wgl16 + (size_t)tid * 8;
#pragma unroll
        for (int j = 0; j < 8; ++j) dst[j] = (_Float16)W[(size_t)(kbase + j) * HC + n];
    } else if (tid < 13312) {
        const int f = tid - 12288;
        const int lane = f & 63;
        const int ks = (f >> 6) & 3;
        const int n4 = f >> 8;
        const int kbase = ks * 32 + (lane >> 4) * 8;
        const int n = n4 * 16 + (lane & 15);
        _Float16* dst = wpp16 + (size_t)f * 8;
#pragma unroll
        for (int j = 0; j < 8; ++j) dst[j] = (_Float16)Wp[(size_t)(kbase + j) * OC + n];
    } else if (tid < 13312 + NL * HC) {
        const int i = tid - 13312;
        bsum[i] = bg[i] + bl[i];
        const float sc = bn_g[i] * rsqrtf(bn_rv[i] + BN_EPS);
        bnsc[i] = sc;
        bnsh[i] = bn_b[i] - bn_rm[i] * sc;
    }
}

// ---------------- x fp32 -> fp16, channel-blocked [4][NPAD][32] ----------------
__global__ void conv_x16(const float* __restrict__ x, _Float16* __restrict__ xblk) {
    const int i = blockIdx.x * blockDim.x + threadIdx.x;
    if (i >= NN * (HC / 4)) return;
    const int node = i >> 5;
    const int c4 = i & 31;          // which float4 within the row
    const int c = c4 * 4;
    const int b = c >> 5;
    const int w = c & 31;
    const float4 v = reinterpret_cast<const float4*>(x)[i];
    half4 o = {(_Float16)v.x, (_Float16)v.y, (_Float16)v.z, (_Float16)v.w};
    *reinterpret_cast<half4*>(xblk + (size_t)b * NPAD * 32 + (size_t)node * 32 + w) = o;
}

// ---------------- dual GEMM via MFMA, blocked-channel I/O ----------------
// hsblk = dinv[row] * (x@Wg);  preblk = x@Wl + bsum + dinv^2 * (x@Wg)
__global__ __launch_bounds__(256) void gemm_dual_mfma(
    const _Float16* __restrict__ xblk,
    const _Float16* __restrict__ Wgp, const _Float16* __restrict__ Wlp,
    const float* __restrict__ bsum, const float* __restrict__ dinv,
    _Float16* __restrict__ hsblk, _Float16* __restrict__ preblk)
{
    const int wave = threadIdx.x >> 6;
    const int lane = threadIdx.x & 63;
    const int rowBase = blockIdx.x * 64 + wave * 16;
    const int ar = rowBase + (lane & 15);
    const int ak = (lane >> 4) * 8;

    half8 a[4];
#pragma unroll
    for (int ks = 0; ks < 4; ++ks)
        a[ks] = *reinterpret_cast<const half8*>(xblk + (size_t)ks * NPAD * 32 + (size_t)ar * 32 + ak);

    f32x4 accG[8], accL[8];
#pragma unroll
    for (int n4 = 0; n4 < 8; ++n4) { accG[n4] = (f32x4)0.f; accL[n4] = (f32x4)0.f; }

    const half8* wg = reinterpret_cast<const half8*>(Wgp) + lane;
    const half8* wl = reinterpret_cast<const half8*>(Wlp) + lane;
#pragma unroll
    for (int n4 = 0; n4 < 8; ++n4) {
#pragma unroll
        for (int ks = 0; ks < 4; ++ks) {
            const half8 bG = wg[(n4 * 4 + ks) * 64];
            accG[n4] = __builtin_amdgcn_mfma_f32_16x16x32_f16(a[ks], bG, accG[n4], 0, 0, 0);
            const half8 bL = wl[(n4 * 4 + ks) * 64];
            accL[n4] = __builtin_amdgcn_mfma_f32_16x16x32_f16(a[ks], bL, accL[n4], 0, 0, 0);
        }
    }

    const int col = lane & 15;
    const int roff = (lane >> 4) * 4;
#pragma unroll
    for (int r = 0; r < 4; ++r) {
        const int row = rowBase + roff + r;
        if (row >= NN) continue;
        const float dv = dinv[row];
        const float selfn = dv * dv;
#pragma unroll
        for (int n4 = 0; n4 < 8; ++n4) {
            const int b = n4 >> 1;
            const int w = (n4 & 1) * 16 + col;
            const size_t idx = (size_t)b * NPAD * 32 + (size_t)row * 32 + w;
            const float hval = accG[n4][r];
            hsblk[idx] = (_Float16)(dv * hval);
            preblk[idx] = (_Float16)(accL[n4][r] + bsum[n4 * 16 + col] + selfn * hval);
        }
    }
}

// ---------------- gather pass over one 32-channel slice ----------------
// Quarter-wave (16 lanes, h2 each) per node; idx loads are 16-lane broadcasts;
// manual 4-deep unroll for memory-level parallelism. hb slice = 3.2 MB, L2-resident.
__global__ __launch_bounds__(256) void gather_pass(
    const unsigned short* __restrict__ csr_src, const int* __restrict__ offs,
    const int* __restrict__ cnt, const float* __restrict__ dinv,
    const _Float16* __restrict__ hb,   // hs slice [NPAD][32]
    const _Float16* __restrict__ pb,   // pre slice [NPAD][32]
    _Float16* __restrict__ xb,         // xout slice [NPAD][32]
    const float* __restrict__ sc32, const float* __restrict__ sh32)  // 32 floats each
{
    const int node = (int)(blockIdx.x * 16 + (threadIdx.x >> 4));
    const int li = threadIdx.x & 15;
    const int beg = offs[node];
    const int n = cnt[node];

    float a0 = 0.f, a1 = 0.f;
    int j = 0;
    for (; j + 4 <= n; j += 4) {
        const int s0 = csr_src[beg + j];
        const int s1 = csr_src[beg + j + 1];
        const int s2 = csr_src[beg + j + 2];
        const int s3 = csr_src[beg + j + 3];
        const h2 v0 = *reinterpret_cast<const h2*>(hb + (size_t)s0 * 32 + li * 2);
        const h2 v1 = *reinterpret_cast<const h2*>(hb + (size_t)s1 * 32 + li * 2);
        const h2 v2 = *reinterpret_cast<const h2*>(hb + (size_t)s2 * 32 + li * 2);
        const h2 v3 = *reinterpret_cast<const h2*>(hb + (size_t)s3 * 32 + li * 2);
        a0 += (float)v0[0] + (float)v1[0] + (float)v2[0] + (float)v3[0];
        a1 += (float)v0[1] + (float)v1[1] + (float)v2[1] + (float)v3[1];
    }
    for (; j < n; ++j) {
        const int s0 = csr_src[beg + j];
        const h2 v0 = *reinterpret_cast<const h2*>(hb + (size_t)s0 * 32 + li * 2);
        a0 += (float)v0[0];
        a1 += (float)v0[1];
    }

    const float dv = dinv[node];
    const h2 pv = __builtin_nontemporal_load(
        reinterpret_cast<const h2*>(pb + (size_t)node * 32 + li * 2));
    const float2 scv = reinterpret_cast<const float2*>(sc32)[li];
    const float2 shv = reinterpret_cast<const float2*>(sh32)[li];
    h2 o;
    o[0] = (_Float16)fmaxf(((float)pv[0] + dv * a0) * scv.x + shv.x, 0.f);
    o[1] = (_Float16)fmaxf(((float)pv[1] + dv * a1) * scv.y + shv.y, 0.f);
    __builtin_nontemporal_store(o, reinterpret_cast<h2*>(xb + (size_t)node * 32 + li * 2));
}

// ---------------- output projection via MFMA (blocked-channel input) ----------------
__global__ __launch_bounds__(256) void gemm_out_mfma(
    const _Float16* __restrict__ xblk, const _Float16* __restrict__ Wpp,
    const float* __restrict__ bp, float* __restrict__ out)
{
    const int wave = threadIdx.x >> 6;
    const int lane = threadIdx.x & 63;
    const int rowBase = blockIdx.x * 64 + wave * 16;
    const int ar = rowBase + (lane & 15);
    const int ak = (lane >> 4) * 8;

    half8 a[4];
#pragma unroll
    for (int ks = 0; ks < 4; ++ks)
        a[ks] = *reinterpret_cast<const half8*>(xblk + (size_t)ks * NPAD * 32 + (size_t)ar * 32 + ak);

    f32x4 acc[4];
#pragma unroll
    for (int n4 = 0; n4 < 4; ++n4) acc[n4] = (f32x4)0.f;

    const half8* wp = reinterpret_cast<const half8*>(Wpp) + lane;
#pragma unroll
    for (int n4 = 0; n4 < 4; ++n4)
#pragma unroll
        for (int ks = 0; ks < 4; ++ks)
            acc[n4] = __builtin_amdgcn_mfma_f32_16x16x32_f16(a[ks], wp[(n4 * 4 + ks) * 64], acc[n4], 0, 0, 0);

    const int col = lane & 15;
    const int roff = (lane >> 4) * 4;
#pragma unroll
    for (int r = 0; r < 4; ++r) {
        const int row = rowBase + roff + r;
        if (row >= NN) continue;
        float* op = out + (size_t)row * OC + col;
#pragma unroll
        for (int n4 = 0; n4 < 4; ++n4)
            op[n4 * 16] = acc[n4][r] + bp[n4 * 16 + col];
    }
}

extern "C" void kernel_launch(void* const* d_in, const int* in_sizes, int n_in,
                              void* d_out, int out_size, void* d_ws, size_t ws_size,
                              hipStream_t stream) {
    const float* x    = (const float*)d_in[0];
    const int*   ei   = (const int*)d_in[1];
    const float* Wg   = (const float*)d_in[2];
    const float* bg   = (const float*)d_in[3];
    const float* Wl   = (const float*)d_in[4];
    const float* bl   = (const float*)d_in[5];
    const float* bn_g = (const float*)d_in[6];
    const float* bn_b = (const float*)d_in[7];
    const float* bn_rm= (const float*)d_in[8];
    const float* bn_rv= (const float*)d_in[9];
    const float* Wp   = (const float*)d_in[10];
    const float* bp   = (const float*)d_in[11];
    float* out = (float*)d_out;

    const int* e_src = ei;
    const int* e_dst = ei + NE;

    // workspace layout
    char* p = (char*)d_ws;
    _Float16* x16a = (_Float16*)p;            p += (size_t)NPAD * HC * 2;   // blocked [4][NPAD][32]
    _Float16* x16b = (_Float16*)p;            p += (size_t)NPAD * HC * 2;
    _Float16* hs16 = (_Float16*)p;            p += (size_t)NPAD * HC * 2;
    _Float16* pre16= (_Float16*)p;            p += (size_t)NPAD * HC * 2;
    float* dinv    = (float*)p;               p += (size_t)NN * 4;
    unsigned short* csr_src = (unsigned short*)p;  p += (size_t)NE * 2;
    unsigned short* rank    = (unsigned short*)p;  p += (size_t)NE * 2;
    int* cnt       = (int*)p;                 p += (size_t)NN * 4;
    int* offs      = (int*)p;                 p += (size_t)NN * 4;
    int* partials  = (int*)p;                 p += (size_t)NB * 4 + 64;
    _Float16* wgl16 = (_Float16*)p;           p += (size_t)12288 * 8 * 2;
    _Float16* wpp16 = (_Float16*)p;           p += (size_t)1024 * 8 * 2;
    float* bsum    = (float*)p;               p += (size_t)NL * HC * 4;
    float* bnsc    = (float*)p;               p += (size_t)NL * HC * 4;
    float* bnsh    = (float*)p;               p += (size_t)NL * HC * 4;

    const int nblk = (NN + 255) / 256;
    const int eblk = (NE + 255) / 256;

    init_cnt<<<nblk, 256, 0, stream>>>(cnt);
    count_deg<<<eblk, 256, 0, stream>>>(e_dst, cnt, rank);
    calc_dinv<<<nblk, 256, 0, stream>>>(cnt, dinv);
    scan1<<<NB, 256, 0, stream>>>(cnt, offs, partials);
    scan2<<<1, 64, 0, stream>>>(partials);
    scan3<<<nblk, 256, 0, stream>>>(offs, partials);
    fill_csr<<<eblk, 256, 0, stream>>>(e_src, e_dst, offs, rank, csr_src);

    pack_params<<<(13312 + NL * HC + 255) / 256, 256, 0, stream>>>(
        Wg, Wl, Wp, bg, bl, bn_g, bn_b, bn_rm, bn_rv,
        wgl16, wpp16, bsum, bnsc, bnsh);
    conv_x16<<<(NN * (HC / 4) + 255) / 256, 256, 0, stream>>>(x, x16a);

    const int gemm_blocks = NPAD / 64;       // 782
    const int gat_blocks = NN / 16;          // 3125 (exact)

    _Float16* xin16 = x16a;
    _Float16* pp16[NL] = {x16b, x16a, x16b};
    for (int l = 0; l < NL; ++l) {
        _Float16* xnext16 = pp16[l];
        gemm_dual_mfma<<<gemm_blocks, 256, 0, stream>>>(
            xin16,
            wgl16 + (size_t)(l * 2 + 0) * 2048 * 8,
            wgl16 + (size_t)(l * 2 + 1) * 2048 * 8,
            bsum + (size_t)l * HC, dinv, hs16, pre16);
        for (int ps = 0; ps < 4; ++ps) {
            gather_pass<<<gat_blocks, 256, 0, stream>>>(
                csr_src, offs, cnt, dinv,
                hs16 + (size_t)ps * NPAD * 32,
                pre16 + (size_t)ps * NPAD * 32,
                xnext16 + (size_t)ps * NPAD * 32,
                bnsc + (size_t)l * HC + ps * 32,
                bnsh + (size_t)l * HC + ps * 32);
        }
        xin16 = xnext16;
    }

    gemm_out_mfma<<<gemm_blocks, 256, 0, stream>>>(xin16, wpp16, bp, out);
}